// Round 1
// baseline (96.043 us; speedup 1.0000x reference)
//
#include <hip/hip_runtime.h>

// Problem constants (match reference setup_inputs)
#define BB 256
#define SS 2048
#define VV 100000
#define EE 128

// Kernel 1: proj[v] = dot(emb[v, :], fc_w)  for v in [0, V)
// One 64-lane wave handles 2 consecutive rows: lanes 0-31 -> row v,
// lanes 32-63 -> row v+1. Each lane loads one float4 (16B); the full wave
// reads 1024B contiguous (two 512B rows). Butterfly shfl_xor reduce within
// each 32-lane half (xor offsets <= 16 stay inside the half).
__global__ __launch_bounds__(256) void proj_kernel(const float* __restrict__ emb,
                                                   const float* __restrict__ fc_w,
                                                   float* __restrict__ proj) {
    const int tid  = blockIdx.x * blockDim.x + threadIdx.x;
    const int lane = threadIdx.x & 63;
    const int wave = tid >> 6;                 // global wave id
    const int v    = wave * 2 + (lane >> 5);   // row for this half-wave
    if (v >= VV) return;

    const float4* __restrict__ emb4 = (const float4*)emb;
    const float4* __restrict__ w4   = (const float4*)fc_w;
    const int sub = lane & 31;                 // position within half-wave

    float4 a = emb4[(size_t)v * (EE / 4) + sub];
    float4 w = w4[sub];
    float p = a.x * w.x + a.y * w.y + a.z * w.z + a.w * w.w;

#pragma unroll
    for (int off = 16; off >= 1; off >>= 1)
        p += __shfl_xor(p, off, 64);

    if (sub == 0) proj[v] = p;
}

// Kernel 2: out[b] = fc_b + (1/len[b]) * sum_{s<len[b]} proj[text[b,s]]
// One 256-thread block per batch row. text reads are coalesced; proj gathers
// hit a 400KB table (L2/L3 resident).
__global__ __launch_bounds__(256) void pool_kernel(const int* __restrict__ text,
                                                   const int* __restrict__ lengths,
                                                   const float* __restrict__ proj,
                                                   const float* __restrict__ fc_b,
                                                   float* __restrict__ out) {
    const int b   = blockIdx.x;
    const int tid = threadIdx.x;
    const int len = lengths[b];
    const int* __restrict__ row = text + (size_t)b * SS;

    float sum = 0.0f;
    for (int s = tid; s < len; s += 256)
        sum += proj[row[s]];

    // wave reduce (64 lanes)
#pragma unroll
    for (int off = 32; off >= 1; off >>= 1)
        sum += __shfl_xor(sum, off, 64);

    __shared__ float ws[4];
    if ((tid & 63) == 0) ws[tid >> 6] = sum;
    __syncthreads();

    if (tid == 0) {
        float total = ws[0] + ws[1] + ws[2] + ws[3];
        out[b] = total / (float)len + fc_b[0];
    }
}

extern "C" void kernel_launch(void* const* d_in, const int* in_sizes, int n_in,
                              void* d_out, int out_size, void* d_ws, size_t ws_size,
                              hipStream_t stream) {
    const int*   text    = (const int*)d_in[0];   // [B, S]
    const int*   lengths = (const int*)d_in[1];   // [B]
    const float* emb     = (const float*)d_in[2]; // [V, E]
    const float* fc_w    = (const float*)d_in[3]; // [1, E]
    const float* fc_b    = (const float*)d_in[4]; // [1]
    float*       out     = (float*)d_out;         // [B, 1]
    float*       proj    = (float*)d_ws;          // V floats = 400 KB scratch

    // Kernel 1: 50000 waves (2 rows each), 4 waves/block -> 12500 blocks
    const int waves  = (VV + 1) / 2;
    const int blocks = (waves + 3) / 4;
    proj_kernel<<<blocks, 256, 0, stream>>>(emb, fc_w, proj);

    // Kernel 2: one block per batch row
    pool_kernel<<<BB, 256, 0, stream>>>(text, lengths, proj, fc_b, out);
}